// Round 2
// baseline (240.331 us; speedup 1.0000x reference)
//
#include <hip/hip_runtime.h>

typedef unsigned short u16;
typedef unsigned int u32;
typedef __attribute__((ext_vector_type(8))) _Float16 half8;
typedef __attribute__((ext_vector_type(4))) float f32x4;

#define MFMA16(A, B, C) __builtin_amdgcn_mfma_f32_16x16x32_f16(A, B, C, 0, 0, 0)

constexpr int BN = 8;     // batches
constexpr int S = 4096;   // seq len (enc and dec)
constexpr int D = 256;    // feature dim
constexpr int KB = 32;    // K/V tile rows per iteration
constexpr int NT = S / KB;

__device__ __forceinline__ u32 pk2h(float a, float b) {
  union { _Float16 h[2]; u32 u; } x;
  x.h[0] = (_Float16)a; x.h[1] = (_Float16)b;
  return x.u;
}

__device__ __forceinline__ void gload_lds16(const void* g, void* l) {
  __builtin_amdgcn_global_load_lds((__attribute__((address_space(1))) void*)(void*)g,
                                   (__attribute__((address_space(3))) void*)l, 16, 0, 0);
}

// ---------------------------------------------------------------------------
// Convert enc (f32) -> enc_ws  : [b][i][d^((i&7)<<3)]     f16 (row-major, d-fast, swizzled)
//                  -> encT_ws  : [b][d][i^(((d>>1)&3)<<3)] f16 (transposed, i-fast, swizzled)
// ---------------------------------------------------------------------------
__global__ __launch_bounds__(256) void convert_enc(const float* __restrict__ enc,
                                                   u16* __restrict__ enc_ws,
                                                   u16* __restrict__ encT_ws) {
  __shared__ u16 tile[64 * 256];  // 32 KiB, [i_local][d] unswizzled
  const int blk = blockIdx.x;
  const int b = blk & 7;
  const int i0 = (blk >> 3) << 6;  // 64 enc rows per block
  const int t = threadIdx.x;

  const float* src = enc + ((size_t)(b * S + i0)) * D;
  u16* dst = enc_ws + ((size_t)(b * S + i0)) * D;

#pragma unroll
  for (int it = 0; it < 16; ++it) {
    int f4 = it * 256 + t;
    int il = f4 >> 6;          // 0..63
    int d = (f4 & 63) << 2;    // 0..252 step 4
    float4 v = *(const float4*)(src + il * D + d);
    uint2 pk = make_uint2(pk2h(v.x, v.y), pk2h(v.z, v.w));
    *(uint2*)(&tile[il * 256 + d]) = pk;
    int dsw = d ^ ((il & 7) << 3);           // swizzle d bits 3..5 by i&7
    *(uint2*)(dst + il * 256 + dsw) = pk;
  }
  __syncthreads();

  // phase 2: each thread writes one d-row of the transposed copy (64 i's)
  {
    const int d = t;  // 0..255
    const int cxor = (d >> 1) & 3;  // i-chunk swizzle (bits 3..4 of i)
    u16* dstT = encT_ws + ((size_t)(b * 256 + d)) * S + i0;
#pragma unroll
    for (int c = 0; c < 8; ++c) {
      int cs = c ^ cxor;
      u16 v0 = tile[(cs * 8 + 0) * 256 + d];
      u16 v1 = tile[(cs * 8 + 1) * 256 + d];
      u16 v2 = tile[(cs * 8 + 2) * 256 + d];
      u16 v3 = tile[(cs * 8 + 3) * 256 + d];
      u16 v4 = tile[(cs * 8 + 4) * 256 + d];
      u16 v5 = tile[(cs * 8 + 5) * 256 + d];
      u16 v6 = tile[(cs * 8 + 6) * 256 + d];
      u16 v7 = tile[(cs * 8 + 7) * 256 + d];
      uint4 o;
      o.x = (u32)v0 | ((u32)v1 << 16);
      o.y = (u32)v2 | ((u32)v3 << 16);
      o.z = (u32)v4 | ((u32)v5 << 16);
      o.w = (u32)v6 | ((u32)v7 << 16);
      *(uint4*)(dstT + c * 8) = o;
    }
  }
}

// ---------------------------------------------------------------------------
// Flash attention: Q=dec, K=V=enc. Swapped QK^T (S^T), transposed O accumulate.
// Block: 256 thr = 4 waves, each wave owns 16 q rows. KB=32 K/V rows per tile.
// ---------------------------------------------------------------------------
__global__ __launch_bounds__(256, 1) void attn_kernel(const u16* __restrict__ enc_ws,
                                                      const u16* __restrict__ encT_ws,
                                                      const float* __restrict__ dec,
                                                      float* __restrict__ out) {
  __shared__ u16 enc_s[2][KB * D];   // 2 x 16 KiB   [i][d] (d-swizzled)
  __shared__ u16 encT_s[2][D * KB];  // 2 x 16 KiB   [d][i] (i-swizzled)

  const int tid = threadIdx.x;
  const int w = tid >> 6;        // wave 0..3
  const int lane = tid & 63;
  const int g = (lane >> 4) & 3;
  const int l15 = lane & 15;

  const int blk = blockIdx.x;
  const int b = blk & 7;                // batch -> XCD affinity
  const int q0 = (blk >> 3) << 6;       // QBLK = 64
  const int qw = q0 + w * 16;           // this wave's first q row

  const u16* encb = enc_ws + ((size_t)b * S) * D;
  const u16* encTb = encT_ws + ((size_t)b * 256) * S;
  const float* decb = dec + ((size_t)b * S) * D;

  // ---- load Q fragments: B-operand layout, lane holds q=l15, k=kk*32+g*8+j ----
  half8 qf[8];
#pragma unroll
  for (int kk = 0; kk < 8; ++kk) {
    const float* p = decb + (size_t)(qw + l15) * D + kk * 32 + g * 8;
    float4 x = *(const float4*)(p);
    float4 y = *(const float4*)(p + 4);
    union { u32 u[4]; half8 v; } uu;
    uu.u[0] = pk2h(x.x, x.y);
    uu.u[1] = pk2h(x.z, x.w);
    uu.u[2] = pk2h(y.x, y.y);
    uu.u[3] = pk2h(y.z, y.w);
    qf[kk] = uu.v;
  }

  // ---- staging: linear global_load_lds, both tiles, split across 4 waves ----
  auto stage = [&](int buf, int t) {
    const int i0t = t * KB;
    {
      const char* gsrc = (const char*)(encb + (size_t)i0t * D);
      char* lbase = (char*)&enc_s[buf][0];
#pragma unroll
      for (int it = 0; it < 4; ++it) {
        int off = w * 4096 + it * 1024;
        gload_lds16(gsrc + off + lane * 16, lbase + off);
      }
    }
    {
      char* lbase = (char*)&encT_s[buf][0];
#pragma unroll
      for (int it = 0; it < 4; ++it) {
        int off = w * 4096 + it * 1024;
        int x = off + lane * 16;
        int d = x >> 6;       // 64 B per d-row
        int ib = x & 63;
        const char* gsrc = (const char*)(encTb + (size_t)d * S + i0t) + ib;
        gload_lds16(gsrc, lbase + off);
      }
    }
  };

  f32x4 acc[16] = {};          // O^T: [dsub], lane holds d=dsub*16+g*4+r, q=l15
  float mrun = -1e30f;
  float lrun = 0.f;

  stage(0, 0);
  __syncthreads();  // drains vmcnt

  for (int t = 0; t < NT; ++t) {
    const int cur = t & 1;
    if (t + 1 < NT) stage(cur ^ 1, t + 1);

    // ---- S^T = enc . Q^T : A-frag from enc_s (row i, d-fast), B-frag = qf ----
    f32x4 st[2] = {};  // [isub]; lane holds i = isub*16 + g*4 + r, q = l15
    const char* ebase = (const char*)&enc_s[cur][0];
    const int eswz = (l15 & 7) << 4;
#pragma unroll
    for (int isub = 0; isub < 2; ++isub) {
      const int irow = isub * 16 + l15;
#pragma unroll
      for (int kk = 0; kk < 8; ++kk) {
        half8 af = *(const half8*)(ebase + irow * 512 + (((kk * 64) + (g * 16)) ^ eswz));
        st[isub] = MFMA16(af, qf[kk], st[isub]);
      }
    }

    // ---- online softmax, defer-max (THR=8); lane owns one q-column ----
    float tm = fmaxf(fmaxf(fmaxf(st[0][0], st[0][1]), fmaxf(st[0][2], st[0][3])),
                     fmaxf(fmaxf(st[1][0], st[1][1]), fmaxf(st[1][2], st[1][3])));
    tm = fmaxf(tm, __shfl_xor(tm, 16));
    tm = fmaxf(tm, __shfl_xor(tm, 32));
    if (__any(tm > mrun + 8.f)) {
      float mnew = fmaxf(mrun, tm);
      float alpha = __expf(mrun - mnew);
      mrun = mnew;
      lrun *= alpha;
#pragma unroll
      for (int ds = 0; ds < 16; ++ds) {
        acc[ds][0] *= alpha; acc[ds][1] *= alpha;
        acc[ds][2] *= alpha; acc[ds][3] *= alpha;
      }
    }
    float p00 = __expf(st[0][0] - mrun), p01 = __expf(st[0][1] - mrun);
    float p02 = __expf(st[0][2] - mrun), p03 = __expf(st[0][3] - mrun);
    float p10 = __expf(st[1][0] - mrun), p11 = __expf(st[1][1] - mrun);
    float p12 = __expf(st[1][2] - mrun), p13 = __expf(st[1][3] - mrun);
    float rs = ((p00 + p01) + (p02 + p03)) + ((p10 + p11) + (p12 + p13));
    rs += __shfl_xor(rs, 16);
    rs += __shfl_xor(rs, 32);
    lrun += rs;
    // pack P^T to f16 pairs: pk[s][t] holds i = 16s + 4g + 2t + {0,1}
    u32 pk00 = pk2h(p00, p01);
    u32 pk01 = pk2h(p02, p03);
    u32 pk10 = pk2h(p10, p11);
    u32 pk11 = pk2h(p12, p13);
    // redistribute to B-frag layout: word v needs i-pair base 8g+2v
    union { u32 u[4]; half8 v; } bb;
#pragma unroll
    for (int v = 0; v < 4; ++v) {
      int srcg = (2 * g + (v >> 1)) & 3;
      int src = (srcg << 4) | l15;
      u32 lo = (u32)__shfl((int)((v & 1) ? pk01 : pk00), src);
      u32 hi = (u32)__shfl((int)((v & 1) ? pk11 : pk10), src);
      bb.u[v] = (g >> 1) ? hi : lo;
    }
    half8 bfr = bb.v;

    // ---- O^T += encT . P^T : A-frag from encT_s (row d, i-fast) ----
    const char* tbase = (const char*)&encT_s[cur][0];
    const int tswz = ((l15 >> 1) & 3) << 4;
#pragma unroll
    for (int ds = 0; ds < 16; ++ds) {
      const int drow = ds * 16 + l15;
      half8 vf = *(const half8*)(tbase + drow * 64 + ((g * 16) ^ tswz));
      acc[ds] = MFMA16(vf, bfr, acc[ds]);
    }

    __syncthreads();  // next-tile loads landed; all waves done reading cur
  }

  // ---- epilogue: divide by l, store O (transposed in regs -> [q][d] in mem) ----
  {
    float inv = 1.0f / lrun;
    const int qg = qw + l15;
    float* orow = out + ((size_t)(b * S + qg)) * D;
#pragma unroll
    for (int ds = 0; ds < 16; ++ds) {
      orow[ds * 16 + g * 4 + 0] = acc[ds][0] * inv;
      orow[ds * 16 + g * 4 + 1] = acc[ds][1] * inv;
      orow[ds * 16 + g * 4 + 2] = acc[ds][2] * inv;
      orow[ds * 16 + g * 4 + 3] = acc[ds][3] * inv;
    }
  }
}

// ---------------------------------------------------------------------------
extern "C" void kernel_launch(void* const* d_in, const int* in_sizes, int n_in,
                              void* d_out, int out_size, void* d_ws, size_t ws_size,
                              hipStream_t stream) {
  const float* enc = (const float*)d_in[0];
  const float* dec = (const float*)d_in[1];
  float* out = (float*)d_out;

  u16* enc_ws = (u16*)d_ws;                       // 16 MiB
  u16* encT_ws = enc_ws + (size_t)BN * S * D;     // 16 MiB

  convert_enc<<<BN * (S / 64), 256, 0, stream>>>(enc, enc_ws, encT_ws);
  attn_kernel<<<BN * (S / 64), 256, 0, stream>>>(enc_ws, encT_ws, dec, out);
}